// Round 1
// 351.527 us; speedup vs baseline: 1.0597x; 1.0597x over previous
//
#include <hip/hip_runtime.h>
#include <hip/hip_bf16.h>

// RelativeAttention: out = softmax((QK^T + Sh + Sw)/8) V,  Q/K/V = feature @ W^T + b
// B=2, N=4096, D=512, DK=64.  Memory-bound on streaming Sh+Sw (268 MB -> ~43 us floor).
// R4: chunked (32-key) double-buffered bias staging with register prefetch.
//   - LDS 75776 -> 14336 B: occupancy 2 -> 4 blocks/CU (16 waves/CU).
//   - Bias loads for chunk it+1 issued AFTER K/V loads of chunk it (vmcnt retires
//     in order), so QK waits vmcnt<=12 and PV waits vmcnt<=8 while the HBM bias
//     stream stays in flight across the whole compute phase. Drained only at the
//     next iteration's LDS store. Wave-private LDS -> still zero barriers.

typedef short bf16x8 __attribute__((ext_vector_type(8)));
typedef short bf16x4 __attribute__((ext_vector_type(4)));
typedef float f32x4  __attribute__((ext_vector_type(4)));

#if __has_builtin(__builtin_amdgcn_exp2f)
#define EXP2F(x) __builtin_amdgcn_exp2f(x)
#else
#define EXP2F(x) exp2f(x)
#endif
#if __has_builtin(__builtin_amdgcn_rcpf)
#define RCPF(x) __builtin_amdgcn_rcpf(x)
#else
#define RCPF(x) (1.0f / (x))
#endif

__device__ __forceinline__ f32x4 mfma16(bf16x8 a, bf16x8 b, f32x4 c) {
  return __builtin_amdgcn_mfma_f32_16x16x32_bf16(a, b, c, 0, 0, 0);
}
__device__ __forceinline__ short f2b(float x) {
  __hip_bfloat16 h = __float2bfloat16(x);
  return __builtin_bit_cast(short, h);
}
__device__ __forceinline__ float b2f(short s) {
  return __bfloat162float(__builtin_bit_cast(__hip_bfloat16, s));
}
__device__ __forceinline__ void split_hl(float x, short& h, short& l) {
  __hip_bfloat16 bh = __float2bfloat16(x);
  h = __builtin_bit_cast(short, bh);
  l = f2b(x - __bfloat162float(bh));
}

// ---------------- kernel 1: weight fp32 -> bf16 hi/lo ----------------
__global__ void wcvt_kernel(const float* __restrict__ wq, const float* __restrict__ wk,
                            const float* __restrict__ wv,
                            short* __restrict__ wh, short* __restrict__ wl) {
  int idx = (blockIdx.x * 256 + threadIdx.x) * 4;
  int p = idx >> 15;
  int off = idx & 32767;
  const float* src = (p == 0) ? wq : (p == 1) ? wk : wv;
  f32x4 v = *(const f32x4*)(src + off);
  bf16x4 h, l;
#pragma unroll
  for (int j = 0; j < 4; ++j) { short hh, ll; split_hl(v[j], hh, ll); h[j] = hh; l[j] = ll; }
  *(bf16x4*)(wh + p * 32768 + off) = h;
  *(bf16x4*)(wl + p * 32768 + off) = l;
}

// ---------------- kernel 2: projections, p-split across waves ----------------
// Q is pre-scaled by log2(e)/8 so attn does exp2(qk + bias*Cs) directly.
__global__ __launch_bounds__(256) void proj_kernel(
    const float* __restrict__ feat, const short* __restrict__ wh, const short* __restrict__ wl,
    const float* __restrict__ bq, const float* __restrict__ bk, const float* __restrict__ bv,
    short* __restrict__ Qh, short* __restrict__ Ql,
    short* __restrict__ Kh, short* __restrict__ Kl, short* __restrict__ Vt) {
  const int lane = threadIdx.x & 63, wave = threadIdx.x >> 6;
  const int lq = lane & 15, quad = lane >> 4;
  const int wid = blockIdx.x * 4 + wave;   // 0..1535
  const int p = wid >> 9, rg = wid & 511;
  const int rbase = rg * 16;
  const float Cs = 0.18033688011112042f;   // log2(e)/8

  f32x4 acc[4];
#pragma unroll
  for (int t = 0; t < 4; ++t) acc[t] = (f32x4){0.f, 0.f, 0.f, 0.f};

  const float* frow = feat + (size_t)(rbase + lq) * 512 + quad * 8;
  const int wrow = p * 64;
  for (int ks = 0; ks < 16; ++ks) {
    f32x4 f0 = *(const f32x4*)(frow + ks * 32);
    f32x4 f1 = *(const f32x4*)(frow + ks * 32 + 4);
    bf16x8 fh, fl;
#pragma unroll
    for (int j = 0; j < 4; ++j) {
      short hh, ll;
      split_hl(f0[j], hh, ll); fh[j] = hh; fl[j] = ll;
      split_hl(f1[j], hh, ll); fh[j + 4] = hh; fl[j + 4] = ll;
    }
#pragma unroll
    for (int t = 0; t < 4; ++t) {
      const int wo = (wrow + t * 16 + lq) * 512 + ks * 32 + quad * 8;
      bf16x8 wfh = *(const bf16x8*)(wh + wo);
      bf16x8 wfl = *(const bf16x8*)(wl + wo);
      acc[t] = mfma16(fh, wfh, acc[t]);
      acc[t] = mfma16(fl, wfh, acc[t]);
      acc[t] = mfma16(fh, wfl, acc[t]);
    }
  }
  const int b = rbase >> 12, rloc = rbase & 4095;
  if (p == 0) {
#pragma unroll
    for (int t = 0; t < 4; ++t) {
      const int dk = t * 16 + lq;
      const float bb = bq[dk];
#pragma unroll
      for (int r = 0; r < 4; ++r) {
        const int row = rbase + 4 * quad + r;
        short h, l;
        split_hl((acc[t][r] + bb) * Cs, h, l);
        Qh[row * 64 + dk] = h; Ql[row * 64 + dk] = l;
      }
    }
  } else if (p == 1) {
#pragma unroll
    for (int t = 0; t < 4; ++t) {
      const int dk = t * 16 + lq;
      const float bb = bk[dk];
#pragma unroll
      for (int r = 0; r < 4; ++r) {
        const int row = rbase + 4 * quad + r;
        short h, l;
        split_hl(acc[t][r] + bb, h, l);
        Kh[row * 64 + dk] = h; Kl[row * 64 + dk] = l;
      }
    }
  } else {
#pragma unroll
    for (int t = 0; t < 4; ++t) {
      const int dk = t * 16 + lq;
      const float bb = bv[dk];
      bf16x4 vpack;
#pragma unroll
      for (int r = 0; r < 4; ++r) vpack[r] = f2b(acc[t][r] + bb);
      *(bf16x4*)(Vt + (size_t)(b * 64 + dk) * 4096 + rloc + 4 * quad) = vpack;
    }
  }
}

// ---------------- kernel 3: fused biased attention, split-K ----------------
// grid = B(2) * qtiles(64) * splits(8) = 1024 blocks, 256 threads (4 waves).
// Per wave, 16 chunks of 32 keys, pipeline depth 1:
//   top:   convert+store chunk it (regs -> LDS buf[it&1])  [drains bias vmcnt]
//   issue: K(4) + V(4) loads for chunk it, then bias(8) nontemporal loads for it+1
//   body:  QK (waits K, vmcnt<=12) -> bias add from LDS + exp2 -> P (LDS)
//          -> PV (waits V, vmcnt<=8).  Bias stays in flight across the body.
__global__ __launch_bounds__(256, 4) void attn_kernel(
    const float* __restrict__ Sh, const float* __restrict__ Sw,
    const short* __restrict__ Qh, const short* __restrict__ Ql,
    const short* __restrict__ Kh, const short* __restrict__ Vt,
    float* __restrict__ Opart, float* __restrict__ lpart) {
  __shared__ short Plds[4][16][40];        // per-wave P[q16][key32] bf16, pad to 16B stride
  __shared__ short BiasLds[4][2][16][36];  // per-wave dbuf (Sh+Sw)*Cs [q16][key32] bf16
  const int bid = blockIdx.x;
  const int sp = bid & 7, qt = (bid >> 3) & 63, b = bid >> 9;
  const int tid = threadIdx.x;
  const int wave = tid >> 6, lane = tid & 63, lq = lane & 15, quad = lane >> 4;
  const int qbase = qt * 64 + wave * 16;
  const float Cs = 0.18033688011112042f;  // log2(e)/8 (Q already pre-scaled)

  const float* shp = Sh + (size_t)(b * 4096 + qbase) * 4096 + sp * 512;
  const float* swp = Sw + (size_t)(b * 4096 + qbase) * 4096 + sp * 512;
  // chunk-load lane mapping: 8 rows x 128B contiguous per instruction
  const int lrow = lane >> 3;        // 0..7  (row = j*8 + lrow)
  const int lcol = (lane & 7) * 4;   // 0..28 (floats)

  // ---- prologue: chunk-0 bias loads first (oldest in the vmcnt stream) ----
  f32x4 sa[2], sc[2];
#pragma unroll
  for (int j = 0; j < 2; ++j) {
    const size_t off = (size_t)(j * 8 + lrow) * 4096 + lcol;
    sa[j] = __builtin_nontemporal_load((const f32x4*)(shp + off));
    sc[j] = __builtin_nontemporal_load((const f32x4*)(swp + off));
  }

  // Q B-fragments (L2-hot, younger than bias0 so they drain with the first K-wait)
  const int qidx = (b * 4096 + qbase + lq) * 64 + quad * 8;
  const bf16x8 qfh0 = *(const bf16x8*)(Qh + qidx);
  const bf16x8 qfh1 = *(const bf16x8*)(Qh + qidx + 32);
  const bf16x8 qfl0 = *(const bf16x8*)(Ql + qidx);
  const bf16x8 qfl1 = *(const bf16x8*)(Ql + qidx + 32);

  f32x4 accO[4];
#pragma unroll
  for (int u = 0; u < 4; ++u) accO[u] = (f32x4){0.f, 0.f, 0.f, 0.f};
  float lsum = 0.f;
  short* pw = &Plds[wave][0][0];
  short* bw = &BiasLds[wave][0][0][0];
  const short* vbase = Vt + (size_t)b * 64 * 4096;

#pragma unroll 2
  for (int it = 0; it < 16; ++it) {
    const int cur = it & 1;
    short* bwc = bw + cur * 576;  // 16*36 shorts per buffer

    // ---- convert + store chunk it into buf[cur] (compiler inserts the vmcnt
    //      wait for sa/sc; K/V loads below may hoist above it harmlessly) ----
#pragma unroll
    for (int j = 0; j < 2; ++j) {
      f32x4 s = (sa[j] + sc[j]) * Cs;
      bf16x4 pk;
#pragma unroll
      for (int r = 0; r < 4; ++r) pk[r] = f2b(s[r]);
      *(bf16x4*)(bwc + (j * 8 + lrow) * 36 + lcol) = pk;
    }

    const int kb = sp * 512 + it * 32;
    // ---- K and V loads for THIS chunk (L2-hot) — must precede bias prefetch ----
    bf16x8 kh0[2], kh1[2];
#pragma unroll
    for (int t = 0; t < 2; ++t) {
      const int kidx = (b * 4096 + kb + t * 16 + lq) * 64 + quad * 8;
      kh0[t] = *(const bf16x8*)(Kh + kidx);
      kh1[t] = *(const bf16x8*)(Kh + kidx + 32);
    }
    bf16x8 vf[4];
#pragma unroll
    for (int u = 0; u < 4; ++u)
      vf[u] = *(const bf16x8*)(vbase + (size_t)(u * 16 + lq) * 4096 + kb + quad * 8);
    __builtin_amdgcn_sched_barrier(0);

    // ---- bias prefetch for chunk it+1 (HBM, youngest in vmcnt stream) ----
    if (it < 15) {
#pragma unroll
      for (int j = 0; j < 2; ++j) {
        const size_t off = (size_t)(j * 8 + lrow) * 4096 + (it + 1) * 32 + lcol;
        sa[j] = __builtin_nontemporal_load((const f32x4*)(shp + off));
        sc[j] = __builtin_nontemporal_load((const f32x4*)(swp + off));
      }
    }
    __builtin_amdgcn_sched_barrier(0);

    // ---- QK^T transposed: accS[t][r] = score[key=16t+4quad+r][q=lq] ----
    f32x4 accS[2];
#pragma unroll
    for (int t = 0; t < 2; ++t) accS[t] = (f32x4){0.f, 0.f, 0.f, 0.f};
#pragma unroll
    for (int t = 0; t < 2; ++t) {
      accS[t] = mfma16(kh0[t], qfh0, accS[t]);
      accS[t] = mfma16(kh1[t], qfh1, accS[t]);
      accS[t] = mfma16(kh0[t], qfl0, accS[t]);
      accS[t] = mfma16(kh1[t], qfl1, accS[t]);
    }

    // ---- bias from LDS, exp2, P write (wave-private, no barriers) ----
#pragma unroll
    for (int t = 0; t < 2; ++t) {
      const bf16x4 bb = *(const bf16x4*)(bwc + lq * 36 + 16 * t + 4 * quad);
      bf16x4 pk;
#pragma unroll
      for (int r = 0; r < 4; ++r) {
        float s = accS[t][r] + b2f(bb[r]);
        float p = EXP2F(s);
        lsum += p;
        pk[r] = f2b(p);
      }
      *(bf16x4*)(pw + lq * 40 + 16 * t + 4 * quad) = pk;
    }

    // ---- PV: A = P[q][key0..31] (one bf16x8/lane), B = Vt rows ----
    const bf16x8 pa = *(const bf16x8*)(pw + lq * 40 + quad * 8);
#pragma unroll
    for (int u = 0; u < 4; ++u) accO[u] = mfma16(pa, vf[u], accO[u]);
  }

  // lsum (q=lq) partial over this lane's keys; reduce across quads
  lsum += __shfl_xor(lsum, 16, 64);
  lsum += __shfl_xor(lsum, 32, 64);

  const int orowW = sp * 8192 + b * 4096 + qbase;
  if (quad == 0) lpart[orowW + lq] = lsum;
#pragma unroll
  for (int u = 0; u < 4; ++u)
#pragma unroll
    for (int r = 0; r < 4; ++r)
      Opart[(size_t)(orowW + 4 * quad + r) * 64 + u * 16 + lq] = accO[u][r];
}

// ---------------- kernel 4: combine splits (float4 + fast rcp) ----------------
__global__ void combine_kernel(const float* __restrict__ Opart, const float* __restrict__ lpart,
                               float* __restrict__ out) {
  const int g = blockIdx.x * 256 + threadIdx.x;  // 0..131071 (x4 floats)
  const int row = g >> 4;
  f32x4 o = (f32x4){0.f, 0.f, 0.f, 0.f};
  float l = 0.f;
#pragma unroll
  for (int s = 0; s < 8; ++s) {
    o += __builtin_nontemporal_load((const f32x4*)(Opart + (size_t)s * 524288 + g * 4));
    l += lpart[s * 8192 + row];
  }
  const float rl = RCPF(l);
  *(f32x4*)(out + g * 4) = o * rl;
}

extern "C" void kernel_launch(void* const* d_in, const int* in_sizes, int n_in,
                              void* d_out, int out_size, void* d_ws, size_t ws_size,
                              hipStream_t stream) {
  const float* feature = (const float*)d_in[0];
  const float* Sh = (const float*)d_in[1];
  const float* Sw = (const float*)d_in[2];
  const float* wq = (const float*)d_in[3];
  const float* bq = (const float*)d_in[4];
  const float* wk = (const float*)d_in[5];
  const float* bk = (const float*)d_in[6];
  const float* wv = (const float*)d_in[7];
  const float* bv = (const float*)d_in[8];

  char* ws = (char*)d_ws;
  const size_t MB = 1u << 20;
  short* Qh = (short*)(ws + 0 * MB);            // 1 MB   (8192*64 bf16)
  short* Ql = (short*)(ws + 1 * MB);            // 1 MB
  short* Kh = (short*)(ws + 2 * MB);            // 1 MB
  short* Kl = (short*)(ws + 3 * MB);            // 1 MB (written by proj, unused in attn)
  short* Vt = (short*)(ws + 4 * MB);            // 1 MB   [b][64][4096]
  short* wh = (short*)(ws + 5 * MB);            // 192 KB
  short* wl = (short*)(ws + 5 * MB + 262144);   // 192 KB
  float* lpart = (float*)(ws + 5 * MB + 524288);// 256 KB [8][8192]
  float* Opart = (float*)(ws + 6 * MB);         // 16.78 MB [8][8192][64]

  wcvt_kernel<<<96, 256, 0, stream>>>(wq, wk, wv, wh, wl);
  proj_kernel<<<384, 256, 0, stream>>>(feature, wh, wl, bq, bk, bv, Qh, Ql, Kh, Kl, Vt);
  attn_kernel<<<1024, 256, 0, stream>>>(Sh, Sw, Qh, Ql, Kh, Vt, Opart, lpart);
  combine_kernel<<<512, 256, 0, stream>>>(Opart, lpart, (float*)d_out);
}